// Round 5
// baseline (787.574 us; speedup 1.0000x reference)
//
#include <hip/hip_runtime.h>
#include <math.h>

#define N_TOK 131072
#define K_CB  1024
#define D_DIM 64
#define MARGIN 0.0625f

// ws layout: en[1024] f32 @0 ; esplit[1024*128] bf16 @4096 ; fixcnt @266240 ; fixlist @266248
#define WS_EN     0
#define WS_ES     4096
#define WS_CNT    266240
#define WS_LIST   266248

typedef short bf16x8 __attribute__((ext_vector_type(8)));
typedef float f32x4  __attribute__((ext_vector_type(4)));

__device__ __forceinline__ ushort f2bf(float f) {   // RNE fp32->bf16
    uint u = __float_as_uint(f);
    u += 0x7FFFu + ((u >> 16) & 1u);
    return (ushort)(u >> 16);
}
__device__ __forceinline__ float bf2f(ushort h) {
    return __uint_as_float(((uint)h) << 16);
}

// ---- prep: en[k] = ||e_k||^2 (exact R1 rounding), esplit = [hi(64) | lo(64)] bf16 per code ----
__global__ void prep_kernel(const float* __restrict__ emb, float* __restrict__ en,
                            ushort* __restrict__ es, uint* __restrict__ fixcnt) {
    int k = blockIdx.x * blockDim.x + threadIdx.x;
    if (k == 0 && blockIdx.x == 0) *fixcnt = 0;
    if (k < K_CB) {
        float s = 0.f;
        #pragma unroll
        for (int d = 0; d < D_DIM; ++d) {
            float v = emb[k * D_DIM + d];
            s = fmaf(v, v, s);
        }
        en[k] = s;
        #pragma unroll
        for (int d = 0; d < D_DIM; ++d) {
            float f = emb[k * D_DIM + d];
            ushort h = f2bf(f);
            es[(size_t)k * 128 + d]      = h;
            es[(size_t)k * 128 + 64 + d] = f2bf(f - bf2f(h));
        }
    }
}

// ---- main: split-bf16 MFMA distances + top-2 argmin, with probs ZERO-FILL interleaved
// into the K-loop (zeros are argmin-independent); epilogue scatters the 1.0s + zq.
// block = 256 thr = 4 waves; block tile = 128 rows.
__global__ __launch_bounds__(256) void vq_main(
    const float* __restrict__ x, const float* __restrict__ emb,
    const float* __restrict__ en, const ushort* __restrict__ es,
    float* __restrict__ zq, float* __restrict__ probs,
    uint* __restrict__ fixcnt, uint* __restrict__ fixlist, uint fixcap)
{
    const int tid  = threadIdx.x;
    const int wave = tid >> 6, lane = tid & 63;
    const int quad = lane >> 4, l15 = lane & 15;
    const int blockRow = blockIdx.x * 128;
    const int waveRow  = blockRow + wave * 32;

    __shared__ uint  lds_k[128];
    __shared__ float lds_en[K_CB];

    // stage en into LDS (decouples the argmin loop from vmcnt)
    {
        f32x4 v = ((const f32x4*)en)[tid];
        ((f32x4*)lds_en)[tid] = v;
    }

    // A-frags per row-group g: [0]=hi d0..31, [1]=hi d32..63, [2]=lo d0..31, [3]=lo d32..63.
    // A layout (m120): A[m=lane&15][k=quad*8+j].
    bf16x8 af[2][4];
    #pragma unroll
    for (int g = 0; g < 2; ++g) {
        const float* xr = x + (size_t)(waveRow + g * 16 + l15) * D_DIM + quad * 8;
        f32x4 p0 = *(const f32x4*)(xr);
        f32x4 p1 = *(const f32x4*)(xr + 4);
        f32x4 p2 = *(const f32x4*)(xr + 32);
        f32x4 p3 = *(const f32x4*)(xr + 36);
        float v0[8], v1[8];
        #pragma unroll
        for (int j = 0; j < 4; ++j) { v0[j] = p0[j]; v0[4 + j] = p1[j]; v1[j] = p2[j]; v1[4 + j] = p3[j]; }
        #pragma unroll
        for (int j = 0; j < 8; ++j) {
            ushort h0 = f2bf(v0[j]);
            af[g][0][j] = (short)h0;
            af[g][2][j] = (short)f2bf(v0[j] - bf2f(h0));
            ushort h1 = f2bf(v1[j]);
            af[g][1][j] = (short)h1;
            af[g][3][j] = (short)f2bf(v1[j] - bf2f(h1));
        }
    }
    __syncthreads();   // lds_en ready

    float b1[8], b2[8]; int k1[8];
    #pragma unroll
    for (int s = 0; s < 8; ++s) { b1[s] = INFINITY; b2[s] = INFINITY; k1[s] = 0; }

    const bf16x8* __restrict__ esv = (const bf16x8*)es;  // 16 frags per code row
    f32x4* __restrict__ probs4 = (f32x4*)probs + (size_t)blockRow * 256;  // block's 512 KB region
    const f32x4 zero4 = {0.f, 0.f, 0.f, 0.f};

    for (int cb = 0; cb < 64; ++cb) {
        const int code = cb * 16 + l15;
        // B-frags: B[k=quad*8+j][n=lane&15]; [0]=hi d0..31, [1]=hi d32..63, [2]=lo d0..31, [3]=lo d32..63
        bf16x8 bfr[4];
        #pragma unroll
        for (int ks = 0; ks < 4; ++ks) bfr[ks] = esv[(size_t)code * 16 + ks * 4 + quad];

        f32x4 acc0 = {0.f, 0.f, 0.f, 0.f};
        f32x4 acc1 = {0.f, 0.f, 0.f, 0.f};
        // dot = xh*eh + xh*el + xl*eh  (xl*el ~1e-4, absorbed by MARGIN)
        acc0 = __builtin_amdgcn_mfma_f32_16x16x32_bf16(af[0][0], bfr[0], acc0, 0, 0, 0);
        acc0 = __builtin_amdgcn_mfma_f32_16x16x32_bf16(af[0][1], bfr[1], acc0, 0, 0, 0);
        acc0 = __builtin_amdgcn_mfma_f32_16x16x32_bf16(af[0][0], bfr[2], acc0, 0, 0, 0);
        acc0 = __builtin_amdgcn_mfma_f32_16x16x32_bf16(af[0][1], bfr[3], acc0, 0, 0, 0);
        acc0 = __builtin_amdgcn_mfma_f32_16x16x32_bf16(af[0][2], bfr[0], acc0, 0, 0, 0);
        acc0 = __builtin_amdgcn_mfma_f32_16x16x32_bf16(af[0][3], bfr[1], acc0, 0, 0, 0);
        acc1 = __builtin_amdgcn_mfma_f32_16x16x32_bf16(af[1][0], bfr[0], acc1, 0, 0, 0);
        acc1 = __builtin_amdgcn_mfma_f32_16x16x32_bf16(af[1][1], bfr[1], acc1, 0, 0, 0);
        acc1 = __builtin_amdgcn_mfma_f32_16x16x32_bf16(af[1][0], bfr[2], acc1, 0, 0, 0);
        acc1 = __builtin_amdgcn_mfma_f32_16x16x32_bf16(af[1][1], bfr[3], acc1, 0, 0, 0);
        acc1 = __builtin_amdgcn_mfma_f32_16x16x32_bf16(af[1][2], bfr[0], acc1, 0, 0, 0);
        acc1 = __builtin_amdgcn_mfma_f32_16x16x32_bf16(af[1][3], bfr[1], acc1, 0, 0, 0);

        const float env = lds_en[code];
        // C layout (m89): col = lane&15 (this lane's code), row = quad*4 + reg.
        #pragma unroll
        for (int r = 0; r < 4; ++r) {
            {
                float d = fmaf(-2.f, acc0[r], env);
                bool lt = d < b1[r];
                b2[r] = lt ? b1[r] : fminf(b2[r], d);
                k1[r] = lt ? code : k1[r];
                b1[r] = lt ? d : b1[r];
            }
            {
                int s = 4 + r;
                float d = fmaf(-2.f, acc1[r], env);
                bool lt = d < b1[s];
                b2[s] = lt ? b1[s] : fminf(b2[s], d);
                k1[s] = lt ? code : k1[s];
                b1[s] = lt ? d : b1[s];
            }
        }

        // interleaved zero-fill of this block's probs region: 8 KB per chunk,
        // 2 x 16B per thread, coalesced; placed after the loads so in-order
        // vmcnt retirement paces the loop at HBM drain rate (the design bound).
        {
            f32x4* p = probs4 + (size_t)cb * 512 + tid * 2;
            __builtin_nontemporal_store(zero4, p);
            __builtin_nontemporal_store(zero4, p + 1);
        }
    }

    // cross-lane top-2 merge over the 16 lanes holding one row's columns
    #pragma unroll
    for (int s = 0; s < 8; ++s) {
        #pragma unroll
        for (int off = 1; off < 16; off <<= 1) {
            float ob1 = __shfl_xor(b1[s], off);
            int   ok1 = __shfl_xor(k1[s], off);
            float ob2 = __shfl_xor(b2[s], off);
            bool better = (ob1 < b1[s]) || (ob1 == b1[s] && ok1 < k1[s]);
            float loser = better ? b1[s] : ob1;
            b1[s] = better ? ob1 : b1[s];
            k1[s] = better ? ok1 : k1[s];
            b2[s] = fminf(fminf(b2[s], ob2), loser);
        }
    }
    if (l15 == 0) {
        #pragma unroll
        for (int s = 0; s < 8; ++s) {
            int g = s >> 2, r = s & 3;
            int lrow = wave * 32 + g * 16 + quad * 4 + r;
            uint word = (uint)k1[s];
            if (b2[s] - b1[s] <= MARGIN) word |= 0x80000000u;   // uncertain -> fixup
            lds_k[lrow] = word;
        }
    }
    __syncthreads();   // also drains vmcnt: all zero-stores globally visible before the 1.0 scatter

    // scatter the 1.0s (one dword per row) + fixup append
    if (tid < 128) {
        uint w = lds_k[tid];
        uint kk = w & 0x3FFu;
        probs[(size_t)(blockRow + tid) * K_CB + kk] = 1.0f;
        if (w & 0x80000000u) {
            uint idx = atomicAdd(fixcnt, 1u);
            if (idx < fixcap) fixlist[idx] = (uint)(blockRow + tid) | (kk << 17);
        }
    }

    // z_q: 128 rows x 16 float4, gather from original fp32 emb (exact copy)
    #pragma unroll
    for (int t = 0; t < 8; ++t) {
        int i = tid + t * 256;
        int r = i >> 4, c = i & 15;
        int kk = (int)(lds_k[r] & 0x3FFu);
        f32x4 v = ((const f32x4*)(emb + (size_t)kk * D_DIM))[c];
        __builtin_nontemporal_store(v, (f32x4*)(zq + (size_t)(blockRow + r) * D_DIM) + c);
    }
}

// ---- fixup: exact fp32 re-argmin (bit-identical to the R1/R2 formula) for flagged rows ----
__global__ __launch_bounds__(256) void vq_fixup(
    const float* __restrict__ x, const float* __restrict__ emb,
    const float* __restrict__ en,
    float* __restrict__ zq, float* __restrict__ probs,
    const uint* __restrict__ fixcnt, const uint* __restrict__ fixlist, uint fixcap)
{
    const int lane = threadIdx.x & 63;
    const uint gwave = (uint)((blockIdx.x * 256 + threadIdx.x) >> 6);
    uint cnt = *fixcnt;
    if (cnt > fixcap) cnt = fixcap;

    for (uint e = gwave; e < cnt; e += 1024u) {
        uint w = fixlist[e];
        int row = (int)(w & 0x1FFFFu);
        int kg  = (int)(w >> 17);
        const float* xr = x + (size_t)row * D_DIM;
        float xn = 0.f;
        #pragma unroll
        for (int d = 0; d < D_DIM; ++d) xn = fmaf(xr[d], xr[d], xn);

        float bd = INFINITY; int bk = 0;
        for (int t = 0; t < 16; ++t) {
            int code = t * 64 + lane;                 // ascending per lane
            const float* er = emb + (size_t)code * D_DIM;
            float a0 = 0.f, a1 = 0.f, a2 = 0.f, a3 = 0.f;
            #pragma unroll
            for (int d = 0; d < D_DIM; d += 4) {
                a0 = fmaf(xr[d + 0], er[d + 0], a0);
                a1 = fmaf(xr[d + 1], er[d + 1], a1);
                a2 = fmaf(xr[d + 2], er[d + 2], a2);
                a3 = fmaf(xr[d + 3], er[d + 3], a3);
            }
            float acc = (a0 + a1) + (a2 + a3);
            float dist = fmaf(-2.f, acc, xn + en[code]);
            if (dist < bd) { bd = dist; bk = code; }
        }
        #pragma unroll
        for (int off = 1; off < 64; off <<= 1) {
            float od = __shfl_xor(bd, off);
            int   ok = __shfl_xor(bk, off);
            if (od < bd || (od == bd && ok < bk)) { bd = od; bk = ok; }
        }
        if (bk != kg) {
            if (lane == 0) {
                probs[(size_t)row * K_CB + kg] = 0.f;
                probs[(size_t)row * K_CB + bk] = 1.f;
            }
            if (lane < 16)
                ((f32x4*)(zq + (size_t)row * D_DIM))[lane] =
                    ((const f32x4*)(emb + (size_t)bk * D_DIM))[lane];
        }
    }
}

extern "C" void kernel_launch(void* const* d_in, const int* in_sizes, int n_in,
                              void* d_out, int out_size, void* d_ws, size_t ws_size,
                              hipStream_t stream) {
    const float* x   = (const float*)d_in[0];   // [N, D] fp32
    const float* emb = (const float*)d_in[1];   // [K, D] fp32
    float* zq    = (float*)d_out;                              // [N, D]
    float* probs = (float*)d_out + (size_t)N_TOK * D_DIM;      // [N, K]

    char* ws = (char*)d_ws;
    float*  en      = (float*)(ws + WS_EN);
    ushort* es      = (ushort*)(ws + WS_ES);
    uint*   fixcnt  = (uint*)(ws + WS_CNT);
    uint*   fixlist = (uint*)(ws + WS_LIST);
    uint fixcap = (ws_size > WS_LIST + 4) ? (uint)((ws_size - WS_LIST) / 4) : 0u;

    prep_kernel<<<K_CB / 256, 256, 0, stream>>>(emb, en, es, fixcnt);
    vq_main<<<N_TOK / 128, 256, 0, stream>>>(x, emb, en, es, zq, probs, fixcnt, fixlist, fixcap);
    vq_fixup<<<256, 256, 0, stream>>>(x, emb, en, zq, probs, fixcnt, fixlist, fixcap);
}

// Round 6
// 772.973 us; speedup vs baseline: 1.0189x; 1.0189x over previous
//
#include <hip/hip_runtime.h>
#include <math.h>

#define N_TOK 131072
#define K_CB  1024
#define D_DIM 64
#define MARGIN 0.0625f

// ws layout: en[1024] f32 @0 ; esplit[1024*128] bf16 @4096 ; fixcnt @266240 ; fixlist @266248
#define WS_EN     0
#define WS_ES     4096
#define WS_CNT    266240
#define WS_LIST   266248

#define FILL_BLOCKS 2048   // zero-fill portion of kernel 1
#define PREP_BLOCKS 16     // prep portion of kernel 1

typedef short bf16x8 __attribute__((ext_vector_type(8)));
typedef float f32x4  __attribute__((ext_vector_type(4)));

__device__ __forceinline__ ushort f2bf(float f) {   // RNE fp32->bf16
    uint u = __float_as_uint(f);
    u += 0x7FFFu + ((u >> 16) & 1u);
    return (ushort)(u >> 16);
}
__device__ __forceinline__ float bf2f(ushort h) {
    return __uint_as_float(((uint)h) << 16);
}

// ---- kernel 1: rocclr-style zero-fill of probs (536 MB, plain dwordx4, grid-linear)
// with the tiny prep fused in as 16 extra blocks (hides under the fill's BW time).
__global__ __launch_bounds__(256) void fill_and_prep(
    float* __restrict__ probs, const float* __restrict__ emb,
    float* __restrict__ en, ushort* __restrict__ es, uint* __restrict__ fixcnt)
{
    const int tid = threadIdx.x;
    const int blk = blockIdx.x;
    if (blk < FILL_BLOCKS) {
        // 2048 blocks x 256 thr x 64 x 16B = 536,870,912 B = all of probs
        f32x4* p = (f32x4*)probs + (size_t)blk * 16384 + tid;
        const f32x4 zero4 = {0.f, 0.f, 0.f, 0.f};
        #pragma unroll
        for (int i = 0; i < 64; ++i) p[i * 256] = zero4;
        return;
    }
    // prep blocks: 16 blocks x 64 codes each; thread t: code = base + (t&63),
    // quarter q = t>>6 handles d in [q*16, q*16+16).
    const int pb   = blk - FILL_BLOCKS;
    const int c6   = tid & 63;
    const int q    = tid >> 6;
    const int code = pb * 64 + c6;
    if (pb == 0 && tid == 0) *fixcnt = 0;

    const float* er = emb + (size_t)code * D_DIM;
    #pragma unroll
    for (int j = 0; j < 16; ++j) {
        float f = er[q * 16 + j];
        ushort h = f2bf(f);
        es[(size_t)code * 128 + q * 16 + j]      = h;
        es[(size_t)code * 128 + 64 + q * 16 + j] = f2bf(f - bf2f(h));
    }
    if (q == 0) {
        float s = 0.f;
        #pragma unroll
        for (int d = 0; d < D_DIM; ++d) s = fmaf(er[d], er[d], s);   // R1-sequential rounding
        en[code] = s;
    }
}

// ---- kernel 2: split-bf16 MFMA distances (hi*hi + hi*lo + lo*hi) + top-2 argmin;
// writes ONLY zq + one 1.0 dword per row (zeros already laid down by kernel 1).
// block = 256 thr = 4 waves; block tile = 128 rows.
__global__ __launch_bounds__(256) void vq_main(
    const float* __restrict__ x, const float* __restrict__ emb,
    const float* __restrict__ en, const ushort* __restrict__ es,
    float* __restrict__ zq, float* __restrict__ probs,
    uint* __restrict__ fixcnt, uint* __restrict__ fixlist, uint fixcap)
{
    const int tid  = threadIdx.x;
    const int wave = tid >> 6, lane = tid & 63;
    const int quad = lane >> 4, l15 = lane & 15;
    const int blockRow = blockIdx.x * 128;
    const int waveRow  = blockRow + wave * 32;

    __shared__ uint  lds_k[128];
    __shared__ float lds_en[K_CB];

    { // stage en into LDS (argmin loop then has no scalar/global en reads)
        f32x4 v = ((const f32x4*)en)[tid];
        ((f32x4*)lds_en)[tid] = v;
    }

    // A-frags per row-group g: [0]=hi d0..31, [1]=hi d32..63, [2]=lo d0..31, [3]=lo d32..63.
    // A layout (m120): A[m=lane&15][k=quad*8+j].
    bf16x8 af[2][4];
    #pragma unroll
    for (int g = 0; g < 2; ++g) {
        const float* xr = x + (size_t)(waveRow + g * 16 + l15) * D_DIM + quad * 8;
        f32x4 p0 = *(const f32x4*)(xr);
        f32x4 p1 = *(const f32x4*)(xr + 4);
        f32x4 p2 = *(const f32x4*)(xr + 32);
        f32x4 p3 = *(const f32x4*)(xr + 36);
        float v0[8], v1[8];
        #pragma unroll
        for (int j = 0; j < 4; ++j) { v0[j] = p0[j]; v0[4 + j] = p1[j]; v1[j] = p2[j]; v1[4 + j] = p3[j]; }
        #pragma unroll
        for (int j = 0; j < 8; ++j) {
            ushort h0 = f2bf(v0[j]);
            af[g][0][j] = (short)h0;
            af[g][2][j] = (short)f2bf(v0[j] - bf2f(h0));
            ushort h1 = f2bf(v1[j]);
            af[g][1][j] = (short)h1;
            af[g][3][j] = (short)f2bf(v1[j] - bf2f(h1));
        }
    }
    __syncthreads();   // lds_en ready

    float b1[8], b2[8]; int k1[8];
    #pragma unroll
    for (int s = 0; s < 8; ++s) { b1[s] = INFINITY; b2[s] = INFINITY; k1[s] = 0; }

    const bf16x8* __restrict__ esv = (const bf16x8*)es;  // 16 frags per code row

    for (int cb = 0; cb < 64; ++cb) {
        const int code = cb * 16 + l15;
        // B-frags: B[k=quad*8+j][n=lane&15]; [0]=hi d0..31, [1]=hi d32..63, [2]=lo d0..31, [3]=lo d32..63
        bf16x8 bfr[4];
        #pragma unroll
        for (int ks = 0; ks < 4; ++ks) bfr[ks] = esv[(size_t)code * 16 + ks * 4 + quad];

        f32x4 acc0 = {0.f, 0.f, 0.f, 0.f};
        f32x4 acc1 = {0.f, 0.f, 0.f, 0.f};
        // dot = xh*eh + xh*el + xl*eh  (xl*el ~1e-4, absorbed by MARGIN)
        acc0 = __builtin_amdgcn_mfma_f32_16x16x32_bf16(af[0][0], bfr[0], acc0, 0, 0, 0);
        acc0 = __builtin_amdgcn_mfma_f32_16x16x32_bf16(af[0][1], bfr[1], acc0, 0, 0, 0);
        acc0 = __builtin_amdgcn_mfma_f32_16x16x32_bf16(af[0][0], bfr[2], acc0, 0, 0, 0);
        acc0 = __builtin_amdgcn_mfma_f32_16x16x32_bf16(af[0][1], bfr[3], acc0, 0, 0, 0);
        acc0 = __builtin_amdgcn_mfma_f32_16x16x32_bf16(af[0][2], bfr[0], acc0, 0, 0, 0);
        acc0 = __builtin_amdgcn_mfma_f32_16x16x32_bf16(af[0][3], bfr[1], acc0, 0, 0, 0);
        acc1 = __builtin_amdgcn_mfma_f32_16x16x32_bf16(af[1][0], bfr[0], acc1, 0, 0, 0);
        acc1 = __builtin_amdgcn_mfma_f32_16x16x32_bf16(af[1][1], bfr[1], acc1, 0, 0, 0);
        acc1 = __builtin_amdgcn_mfma_f32_16x16x32_bf16(af[1][0], bfr[2], acc1, 0, 0, 0);
        acc1 = __builtin_amdgcn_mfma_f32_16x16x32_bf16(af[1][1], bfr[3], acc1, 0, 0, 0);
        acc1 = __builtin_amdgcn_mfma_f32_16x16x32_bf16(af[1][2], bfr[0], acc1, 0, 0, 0);
        acc1 = __builtin_amdgcn_mfma_f32_16x16x32_bf16(af[1][3], bfr[1], acc1, 0, 0, 0);

        const float env = lds_en[code];
        // C layout (m89): col = lane&15 (this lane's code), row = quad*4 + reg.
        #pragma unroll
        for (int r = 0; r < 4; ++r) {
            {
                float d = fmaf(-2.f, acc0[r], env);
                bool lt = d < b1[r];
                b2[r] = lt ? b1[r] : fminf(b2[r], d);
                k1[r] = lt ? code : k1[r];
                b1[r] = lt ? d : b1[r];
            }
            {
                int s = 4 + r;
                float d = fmaf(-2.f, acc1[r], env);
                bool lt = d < b1[s];
                b2[s] = lt ? b1[s] : fminf(b2[s], d);
                k1[s] = lt ? code : k1[s];
                b1[s] = lt ? d : b1[s];
            }
        }
    }

    // cross-lane top-2 merge over the 16 lanes holding one row's columns
    #pragma unroll
    for (int s = 0; s < 8; ++s) {
        #pragma unroll
        for (int off = 1; off < 16; off <<= 1) {
            float ob1 = __shfl_xor(b1[s], off);
            int   ok1 = __shfl_xor(k1[s], off);
            float ob2 = __shfl_xor(b2[s], off);
            bool better = (ob1 < b1[s]) || (ob1 == b1[s] && ok1 < k1[s]);
            float loser = better ? b1[s] : ob1;
            b1[s] = better ? ob1 : b1[s];
            k1[s] = better ? ok1 : k1[s];
            b2[s] = fminf(fminf(b2[s], ob2), loser);
        }
    }
    if (l15 == 0) {
        #pragma unroll
        for (int s = 0; s < 8; ++s) {
            int g = s >> 2, r = s & 3;
            int lrow = wave * 32 + g * 16 + quad * 4 + r;
            uint word = (uint)k1[s];
            if (b2[s] - b1[s] <= MARGIN) word |= 0x80000000u;   // uncertain -> fixup
            lds_k[lrow] = word;
        }
    }
    __syncthreads();

    // scatter the 1.0s (one dword per row) + fixup append
    if (tid < 128) {
        uint w = lds_k[tid];
        uint kk = w & 0x3FFu;
        probs[(size_t)(blockRow + tid) * K_CB + kk] = 1.0f;
        if (w & 0x80000000u) {
            uint idx = atomicAdd(fixcnt, 1u);
            if (idx < fixcap) fixlist[idx] = (uint)(blockRow + tid) | (kk << 17);
        }
    }

    // z_q: 128 rows x 16 float4, gather from original fp32 emb (exact copy)
    #pragma unroll
    for (int t = 0; t < 8; ++t) {
        int i = tid + t * 256;
        int r = i >> 4, c = i & 15;
        int kk = (int)(lds_k[r] & 0x3FFu);
        f32x4 v = ((const f32x4*)(emb + (size_t)kk * D_DIM))[c];
        ((f32x4*)(zq + (size_t)(blockRow + r) * D_DIM))[c] = v;
    }
}

// ---- kernel 3: exact fp32 re-argmin (bit-identical to the R1/R2 formula) for flagged rows ----
__global__ __launch_bounds__(256) void vq_fixup(
    const float* __restrict__ x, const float* __restrict__ emb,
    const float* __restrict__ en,
    float* __restrict__ zq, float* __restrict__ probs,
    const uint* __restrict__ fixcnt, const uint* __restrict__ fixlist, uint fixcap)
{
    const int lane = threadIdx.x & 63;
    const uint gwave = (uint)((blockIdx.x * 256 + threadIdx.x) >> 6);
    uint cnt = *fixcnt;
    if (cnt > fixcap) cnt = fixcap;

    for (uint e = gwave; e < cnt; e += 1024u) {
        uint w = fixlist[e];
        int row = (int)(w & 0x1FFFFu);
        int kg  = (int)(w >> 17);
        const float* xr = x + (size_t)row * D_DIM;
        float xn = 0.f;
        #pragma unroll
        for (int d = 0; d < D_DIM; ++d) xn = fmaf(xr[d], xr[d], xn);

        float bd = INFINITY; int bk = 0;
        for (int t = 0; t < 16; ++t) {
            int code = t * 64 + lane;                 // ascending per lane
            const float* er = emb + (size_t)code * D_DIM;
            float a0 = 0.f, a1 = 0.f, a2 = 0.f, a3 = 0.f;
            #pragma unroll
            for (int d = 0; d < D_DIM; d += 4) {
                a0 = fmaf(xr[d + 0], er[d + 0], a0);
                a1 = fmaf(xr[d + 1], er[d + 1], a1);
                a2 = fmaf(xr[d + 2], er[d + 2], a2);
                a3 = fmaf(xr[d + 3], er[d + 3], a3);
            }
            float acc = (a0 + a1) + (a2 + a3);
            float dist = fmaf(-2.f, acc, xn + en[code]);
            if (dist < bd) { bd = dist; bk = code; }
        }
        #pragma unroll
        for (int off = 1; off < 64; off <<= 1) {
            float od = __shfl_xor(bd, off);
            int   ok = __shfl_xor(bk, off);
            if (od < bd || (od == bd && ok < bk)) { bd = od; bk = ok; }
        }
        if (bk != kg) {
            if (lane == 0) {
                probs[(size_t)row * K_CB + kg] = 0.f;
                probs[(size_t)row * K_CB + bk] = 1.f;
            }
            if (lane < 16)
                ((f32x4*)(zq + (size_t)row * D_DIM))[lane] =
                    ((const f32x4*)(emb + (size_t)bk * D_DIM))[lane];
        }
    }
}

extern "C" void kernel_launch(void* const* d_in, const int* in_sizes, int n_in,
                              void* d_out, int out_size, void* d_ws, size_t ws_size,
                              hipStream_t stream) {
    const float* x   = (const float*)d_in[0];   // [N, D] fp32
    const float* emb = (const float*)d_in[1];   // [K, D] fp32
    float* zq    = (float*)d_out;                              // [N, D]
    float* probs = (float*)d_out + (size_t)N_TOK * D_DIM;      // [N, K]

    char* ws = (char*)d_ws;
    float*  en      = (float*)(ws + WS_EN);
    ushort* es      = (ushort*)(ws + WS_ES);
    uint*   fixcnt  = (uint*)(ws + WS_CNT);
    uint*   fixlist = (uint*)(ws + WS_LIST);
    uint fixcap = (ws_size > WS_LIST + 4) ? (uint)((ws_size - WS_LIST) / 4) : 0u;

    fill_and_prep<<<FILL_BLOCKS + PREP_BLOCKS, 256, 0, stream>>>(probs, emb, en, es, fixcnt);
    vq_main<<<N_TOK / 128, 256, 0, stream>>>(x, emb, en, es, zq, probs, fixcnt, fixlist, fixcap);
    vq_fixup<<<256, 256, 0, stream>>>(x, emb, en, zq, probs, fixcnt, fixlist, fixcap);
}